// Round 13
// baseline (151.852 us; speedup 1.0000x reference)
//
#include <hip/hip_runtime.h>
#include <math.h>

#define DM 1024
#define NH 16
#define HD 64
#define SEQ 2048
#define NB2 2
#define MROWS 4096   // NB2*SEQ

typedef unsigned short u16;
typedef __attribute__((ext_vector_type(8))) short short8;
typedef __attribute__((ext_vector_type(4))) float f32x4;
typedef __attribute__((ext_vector_type(2))) unsigned int u32x2;

#define GLOAD16(g, l) __builtin_amdgcn_global_load_lds( \
    (const __attribute__((address_space(1))) void*)(g),  \
    (__attribute__((address_space(3))) void*)(l), 16, 0, 0)

static __device__ __forceinline__ u16 f2bf(float f) {
  union { float f; unsigned u; } v; v.f = f;
  unsigned r = v.u + 0x7fffu + ((v.u >> 16) & 1u);
  return (u16)(r >> 16);
}

static __device__ __forceinline__ short8 cvt8(float4 a, float4 b) {
  short8 s;
  s[0] = (short)f2bf(a.x); s[1] = (short)f2bf(a.y);
  s[2] = (short)f2bf(a.z); s[3] = (short)f2bf(a.w);
  s[4] = (short)f2bf(b.x); s[5] = (short)f2bf(b.y);
  s[6] = (short)f2bf(b.z); s[7] = (short)f2bf(b.w);
  return s;
}

// z=0..3: f32->bf16 conversion of {Wq,Wk,Wv,Wo}; z=4: rope table.
// X (queries/keys/values) conversion is fused into gemm_qkv's A-staging.
__global__ void conv_w(
    const float* __restrict__ wq, const float* __restrict__ wk,
    const float* __restrict__ wv, const float* __restrict__ wo,
    u16* __restrict__ wqb, u16* __restrict__ wkb, u16* __restrict__ wvb, u16* __restrict__ wob,
    float* __restrict__ cosT, float* __restrict__ sinT)
{
  const int z = blockIdx.z;
  const int idx = blockIdx.x * blockDim.x + threadIdx.x;
  if (z == 4) {
    if (idx >= SEQ * 32) return;
    int l = idx >> 5, i = idx & 31;
    float invf = expf(-(float)i * (9.210340371976184f / 32.0f)); // 10000^(-i/32)
    float ang = (float)l * invf;
    float s, c;
    sincosf(ang, &s, &c);
    cosT[idx] = c; sinT[idx] = s;
    return;
  }
  const float* src; u16* dst;
  switch (z) {
    case 0: src = wq; dst = wqb; break;
    case 1: src = wk; dst = wkb; break;
    case 2: src = wv; dst = wvb; break;
    default: src = wo; dst = wob; break;
  }
  const int base = idx * 8;
  if (base >= DM * DM) return;
  float4 a = *(const float4*)(src + base);
  float4 b = *(const float4*)(src + base + 4);
  *(short8*)(dst + base) = cvt8(a, b);
}

// ---------------- 256x256 fused QKV GEMM, f32-A fused conversion ----------------
// C[256x256] = bf16(A_f32)[256xK] x W[256xK]^T (+bias), K=1024. 512 thr / 8 waves
// (2M x 4N). BK=32, 3 LDS buffers (96 KB), phase-split compute (2 x 16 MFMA).
// A staged via reg: 4x global_load_dwordx4 (f32) -> cvt8 -> 2x ds_write_b128
// (conflict-free, 16B-strided). B staged via global_load_lds. Per step s:
//   [vmcnt(2) lgkmcnt(0)] [barrier] write A(s+1)->buf(s+1) |
//   phA: ds_read + load A(s+2)f32 | barrier | 16 MFMA | barrier |
//   phB: ds_read + issue B(s+2)   | barrier | 16 MFMA
// vmcnt(2) retires {B(s), A(s+1)} leaving B(s+1) in flight (never 0 mid-loop).
__global__ __launch_bounds__(512) void gemm_qkv(
    const float* __restrict__ Qf, const float* __restrict__ Kf, const float* __restrict__ Vf,
    const u16* __restrict__ Wqb, const u16* __restrict__ Wkb, const u16* __restrict__ Wvb,
    const float* __restrict__ bq, const float* __restrict__ bk, const float* __restrict__ bv,
    u16* __restrict__ Qb, u16* __restrict__ Kb, u16* __restrict__ VT,
    const float* __restrict__ cosT, const float* __restrict__ sinT)
{
  __shared__ __align__(16) u16 SH[49152];   // 96 KB: 3 x 32KB buffers; reused as bounce
  const int z = blockIdx.z;
  const float* Af = (z == 0) ? Qf : (z == 1) ? Kf : Vf;
  const u16* W = (z == 0) ? Wqb : (z == 1) ? Wkb : Wvb;
  const float* bias = (z == 0) ? bq : (z == 1) ? bk : bv;
  const int row0 = blockIdx.x * 256, col0 = blockIdx.y * 256;

  const int tid = threadIdx.x;
  const int lane = tid & 63;
  const int wid = tid >> 6;       // 0..7
  const int wm = wid >> 2;        // M half (128 rows)
  const int wn = wid & 3;         // N quarter (64 cols)
  const int fr = lane & 15, kg = lane >> 4;
  const int row = tid & 255;      // staged A/B row
  const int h = tid >> 8;         // 0..1: k-half
  const int rw8 = row * 8;

  // A: f32 source, thread covers k [t*32 + h*16, +16) of row (kcg 2h, 2h+1)
  const float* gaf = Af + (size_t)(row0 + row) * DM + h * 16;
  // B: bf16 weights via DMA (unchanged layout)
  const u16* gb = W + (size_t)(col0 + row) * DM + (h << 3);
  const int lw = (wid >> 2) * 2048 + (wid & 3) * 512;   // wave-uniform; lane*16B implicit
  u16* B0 = SH;
  u16* B1 = SH + 16384;
  u16* B2 = SH + 32768;

  f32x4 acc[8][4];
#pragma unroll
  for (int m = 0; m < 8; ++m)
#pragma unroll
    for (int n = 0; n < 4; ++n) acc[m][n] = (f32x4){0.f, 0.f, 0.f, 0.f};

  float4 ar0, ar1, ar2, ar3;   // in-flight A f32 regs (one tile)

  auto loadA = [&](int t) {
    const float* g = gaf + (size_t)t * 32;
    ar0 = *(const float4*)(g);
    ar1 = *(const float4*)(g + 4);
    ar2 = *(const float4*)(g + 8);
    ar3 = *(const float4*)(g + 12);
  };
  auto writeA = [&](u16* buf) {
    *(short8*)(buf + (2 * h) * 2048 + rw8)     = cvt8(ar0, ar1);
    *(short8*)(buf + (2 * h + 1) * 2048 + rw8) = cvt8(ar2, ar3);
  };
  auto issueB = [&](int t, u16* buf) {
    const int ko = t * 32;
    GLOAD16(gb + ko, buf + 8192 + lw);
    GLOAD16(gb + ko + 16, buf + 8192 + lw + 4096);
  };

  auto phA = [&](const u16* bufR, int s, short8* bfr) {
    short8 afr[4];
#pragma unroll
    for (int m = 0; m < 4; ++m)
      afr[m] = *(const short8*)(&bufR[kg * 2048 + (wm * 128 + m * 16 + fr) * 8]);
#pragma unroll
    for (int n = 0; n < 4; ++n)
      bfr[n] = *(const short8*)(&bufR[8192 + kg * 2048 + (wn * 64 + n * 16 + fr) * 8]);
    if (s <= 29) loadA(s + 2);
    __builtin_amdgcn_sched_barrier(0);
    __builtin_amdgcn_s_barrier();
    __builtin_amdgcn_sched_barrier(0);
    __builtin_amdgcn_s_setprio(1);
#pragma unroll
    for (int m = 0; m < 4; ++m)
#pragma unroll
      for (int n = 0; n < 4; ++n)
        acc[m][n] = __builtin_amdgcn_mfma_f32_16x16x32_bf16(afr[m], bfr[n], acc[m][n], 0, 0, 0);
    __builtin_amdgcn_s_setprio(0);
    __builtin_amdgcn_sched_barrier(0);
    __builtin_amdgcn_s_barrier();
    __builtin_amdgcn_sched_barrier(0);
  };
  auto phB = [&](const u16* bufR, u16* bufWB, int s, const short8* bfr) {
    short8 afr[4];
#pragma unroll
    for (int m = 0; m < 4; ++m)
      afr[m] = *(const short8*)(&bufR[kg * 2048 + (wm * 128 + (m + 4) * 16 + fr) * 8]);
    if (s <= 29) issueB(s + 2, bufWB);
    __builtin_amdgcn_sched_barrier(0);
    __builtin_amdgcn_s_barrier();
    __builtin_amdgcn_sched_barrier(0);
    __builtin_amdgcn_s_setprio(1);
#pragma unroll
    for (int m = 0; m < 4; ++m)
#pragma unroll
      for (int n = 0; n < 4; ++n)
        acc[m + 4][n] = __builtin_amdgcn_mfma_f32_16x16x32_bf16(afr[m], bfr[n], acc[m + 4][n], 0, 0, 0);
    __builtin_amdgcn_s_setprio(0);
  };

  // ---- prologue: depth-2 ----
  loadA(0);
  issueB(0, B0);
  asm volatile("s_waitcnt vmcnt(2)" ::: "memory");   // A(0) landed (B(0) in flight)
  writeA(B0);
  loadA(1);
  issueB(1, B1);

#define QSTEP(WLIT, bufR, bufWA, bufWB, s) do {                     \
    asm volatile("s_waitcnt vmcnt(" WLIT ") lgkmcnt(0)" ::: "memory"); \
    __builtin_amdgcn_sched_barrier(0);                              \
    __builtin_amdgcn_s_barrier();                                   \
    __builtin_amdgcn_sched_barrier(0);                              \
    if ((s) <= 30) writeA(bufWA);                                   \
    short8 bfr[4];                                                  \
    phA(bufR, (s), bfr);                                            \
    phB(bufR, bufWB, (s), bfr);                                     \
  } while (0)

  for (int t = 0; t < 30; t += 3) {
    QSTEP("2", B0, B1, B2, t);
    QSTEP("2", B1, B2, B0, t + 1);
    QSTEP("2", B2, B0, B1, t + 2);
  }
  QSTEP("2", B0, B1, B2, 30);
  QSTEP("0", B1, B2, B0, 31);
#undef QSTEP

  if (z == 2) {
    // ---- transposed epilogue: VT[(nb*NH + e/64)*64 + e%64][sbase + s] = C[s][e] ----
    __syncthreads();   // last-step LDS reads done before SH reuse
    const int nb = row0 >> 11;
    const int sbase = row0 & (SEQ - 1);
#pragma unroll
    for (int p = 0; p < 4; ++p) {
      if (wn == p) {
#pragma unroll
        for (int n = 0; n < 4; ++n) {
          const int dcol = n * 16 + fr;
          const float bv = bias[col0 + p * 64 + dcol];
#pragma unroll
          for (int m = 0; m < 8; ++m)
#pragma unroll
            for (int r = 0; r < 4; ++r)
              SH[dcol * 264 + wm * 128 + m * 16 + kg * 4 + r] = f2bf(acc[m][n][r] + bv);
        }
      }
      __syncthreads();
      {
        const int dcol = tid >> 3, sq = tid & 7;   // 64 cols x 8 chunks of 32 u16
        const int e = col0 + p * 64 + dcol;
        u16* dst = VT + ((size_t)(nb * NH + (e >> 6)) * HD + (e & 63)) * SEQ + sbase + sq * 32;
#pragma unroll
        for (int j = 0; j < 4; ++j)
          *(short8*)(dst + j * 8) = *(const short8*)(&SH[dcol * 264 + sq * 32 + j * 8]);
      }
      __syncthreads();
    }
    return;
  }

  // ---- RoPE epilogue (z=0 Q, z=1 K) ----
  const float qscale = (z == 0) ? 0.125f : 1.0f;
  u16* Cb = (z == 0) ? Qb : Kb;
#pragma unroll
  for (int m = 0; m < 8; ++m) {
#pragma unroll
    for (int r = 0; r < 4; ++r) {
      const int rowg = row0 + wm * 128 + m * 16 + kg * 4 + r;
      const int l = rowg & (SEQ - 1);
#pragma unroll
      for (int n = 0; n < 4; ++n) {
        const int colg = col0 + wn * 64 + n * 16 + fr;
        const int i = n * 16 + fr;      // position within head (0..63)
        const int fi = i & 31;          // freq index
        const float c = cosT[l * 32 + fi];
        const float s = sinT[l * 32 + fi];
        const float v = acc[m][n][r] + bias[colg];
        const float pv = acc[m][n ^ 2][r] + bias[col0 + wn * 64 + ((n ^ 2) * 16 + fr)];
        const float o = v * c + ((i < 32) ? -pv : pv) * s;
        Cb[(size_t)rowg * DM + colg] = f2bf(o * qscale);
      }
    }
  }
}

// ---------------- 128x128 output-projection GEMM, phase-split pipeline ----------------
// 256 thr / 4 waves (2M x 2N, 64x64 out each), BK=32, 3 x 16KB buffers, depth-2
// counted vmcnt. Phases of 8 MFMA.
__global__ __launch_bounds__(256) void gemm_o(
    const u16* __restrict__ Ob, const u16* __restrict__ Wob,
    const float* __restrict__ bo, float* __restrict__ out)
{
  __shared__ __align__(16) u16 SH[24576];   // 48 KB
  const int row0 = blockIdx.x * 128, col0 = blockIdx.y * 128;
  const int tid = threadIdx.x;
  const int lane = tid & 63;
  const int w = tid >> 6;         // 0..3
  const int wr = w >> 1;          // M half (64 rows)
  const int wc = w & 1;           // N half (64 cols)
  const int fr = lane & 15, kg = lane >> 4;

  const u16* ga = Ob + (size_t)(row0 + (tid & 127)) * DM + ((tid >> 7) << 3);
  const u16* gb = Wob + (size_t)(col0 + (tid & 127)) * DM + ((tid >> 7) << 3);
  const int lw = w * 512;
  u16* B0 = SH;
  u16* B1 = SH + 8192;
  u16* B2 = SH + 16384;

  f32x4 acc[4][4];
#pragma unroll
  for (int m = 0; m < 4; ++m)
#pragma unroll
    for (int n = 0; n < 4; ++n) acc[m][n] = (f32x4){0.f, 0.f, 0.f, 0.f};

  auto issueA = [&](int t, u16* buf) {
    const int ko = t * 32;
    GLOAD16(ga + ko, buf + lw);
    GLOAD16(ga + ko + 16, buf + lw + 2048);
  };
  auto issueB = [&](int t, u16* buf) {
    const int ko = t * 32;
    GLOAD16(gb + ko, buf + 4096 + lw);
    GLOAD16(gb + ko + 16, buf + 4096 + lw + 2048);
  };

  auto phA = [&](const u16* bufR, u16* bufW, int t2, short8* bfr) {
    short8 afr[2];
#pragma unroll
    for (int m = 0; m < 2; ++m)
      afr[m] = *(const short8*)(&bufR[kg * 1024 + (wr * 64 + m * 16 + fr) * 8]);
#pragma unroll
    for (int n = 0; n < 4; ++n)
      bfr[n] = *(const short8*)(&bufR[4096 + kg * 1024 + (wc * 64 + n * 16 + fr) * 8]);
    if (t2 < 32) issueA(t2, bufW);
    __builtin_amdgcn_sched_barrier(0);
    __builtin_amdgcn_s_barrier();
    __builtin_amdgcn_sched_barrier(0);
    __builtin_amdgcn_s_setprio(1);
#pragma unroll
    for (int m = 0; m < 2; ++m)
#pragma unroll
      for (int n = 0; n < 4; ++n)
        acc[m][n] = __builtin_amdgcn_mfma_f32_16x16x32_bf16(afr[m], bfr[n], acc[m][n], 0, 0, 0);
    __builtin_amdgcn_s_setprio(0);
    __builtin_amdgcn_sched_barrier(0);
    __builtin_amdgcn_s_barrier();
    __builtin_amdgcn_sched_barrier(0);
  };
  auto phB = [&](const u16* bufR, u16* bufW, int t2, const short8* bfr) {
    short8 afr[2];
#pragma unroll
    for (int m = 0; m < 2; ++m)
      afr[m] = *(const short8*)(&bufR[kg * 1024 + (wr * 64 + (m + 2) * 16 + fr) * 8]);
    if (t2 < 32) issueB(t2, bufW);
    __builtin_amdgcn_sched_barrier(0);
    __builtin_amdgcn_s_barrier();
    __builtin_amdgcn_sched_barrier(0);
    __builtin_amdgcn_s_setprio(1);
#pragma unroll
    for (int m = 0; m < 2; ++m)
#pragma unroll
      for (int n = 0; n < 4; ++n)
        acc[m + 2][n] = __builtin_amdgcn_mfma_f32_16x16x32_bf16(afr[m], bfr[n], acc[m + 2][n], 0, 0, 0);
    __builtin_amdgcn_s_setprio(0);
  };

  issueA(0, B0); issueB(0, B0);
  issueA(1, B1); issueB(1, B1);

#define OSTEP(WLIT, bufR, bufW, t2) do {                            \
    asm volatile("s_waitcnt vmcnt(" WLIT ")" ::: "memory");         \
    __builtin_amdgcn_sched_barrier(0);                              \
    __builtin_amdgcn_s_barrier();                                   \
    __builtin_amdgcn_sched_barrier(0);                              \
    short8 bfr[4];                                                  \
    phA(bufR, bufW, t2, bfr);                                       \
    phB(bufR, bufW, t2, bfr);                                       \
  } while (0)

  for (int t = 0; t < 30; t += 3) {
    OSTEP("4", B0, B2, t + 2);
    OSTEP("4", B1, B0, t + 3);
    OSTEP("4", B2, B1, t + 4);
  }
  OSTEP("4", B0, B2, 32);
  OSTEP("0", B1, B2, 33);
#undef OSTEP

#pragma unroll
  for (int m = 0; m < 4; ++m) {
#pragma unroll
    for (int r = 0; r < 4; ++r) {
      const int rowg = row0 + wr * 64 + m * 16 + kg * 4 + r;
#pragma unroll
      for (int n = 0; n < 4; ++n) {
        const int colg = col0 + wc * 64 + n * 16 + fr;
        out[(size_t)rowg * DM + colg] = acc[m][n][r] + bo[colg];
      }
    }
  }
}

// Flash attention, causal, balanced pairing (qbp, 15-qbp), 8 waves x 16 q-rows.
// Swapped QK^T (mfma(K,Q)) -> lane-local softmax; K/V^T staged via XOR-swizzled
// conflict-free LDS; P redistributed through a per-wave LDS strip (no barrier).
__global__ __launch_bounds__(512) void flash_attn(
    const u16* __restrict__ Qp, const u16* __restrict__ Kp,
    const u16* __restrict__ VT, u16* __restrict__ Op)
{
  __shared__ __align__(16) u16 Ks[4096];   // swizzled: chunk c = dc*64 + (s^dc), 16B chunks
  __shared__ __align__(16) u16 Vt[4096];   // swizzled: chunk c = sc*64 + (d^sc)
  __shared__ __align__(16) u16 Pl[9216];   // per-wave P strip: [fr][36 dwords], 144B row stride

  const int tid = threadIdx.x;
  const int lane = tid & 63;
  const int w = tid >> 6;                  // 0..7
  const int fr = lane & 15, rg = lane >> 4;
  const int qbp = blockIdx.x;              // 0..7
  const int h = blockIdx.y, nb = blockIdx.z;

  const size_t headoff = (size_t)nb * SEQ * DM + (size_t)h * HD;      // Q, K, O
  const size_t vthead = (size_t)(nb * NH + h) * HD * SEQ;             // V^T
  const int srow = tid >> 3;   // 0..63 (staging row: s for K, d for V^T)
  const int sch  = tid & 7;    // 16B chunk within row
  u16* Pw = &Pl[w * 1152];

  for (int pass = 0; pass < 2; ++pass) {
    const int qe = pass ? (15 - qbp) : qbp;
    const int KBend = 2 * qe + 2;
    const int qrow0 = qe * 128 + w * 16;
    const int qg = qrow0 + fr;             // this lane's softmax q-row

    short8 qf[2];
#pragma unroll
    for (int ck = 0; ck < 2; ++ck)
      qf[ck] = *(const short8*)(Qp + headoff + (size_t)(qrow0 + fr) * DM + ck * 32 + rg * 8);

    f32x4 accO[4];
#pragma unroll
    for (int df = 0; df < 4; ++df) accO[df] = (f32x4){0.f, 0.f, 0.f, 0.f};
    float m_run = -3e38f, l_run = 0.f;

    // prefetch kb=0 (one 16B chunk of K and V^T per thread)
    short8 kpf = *(const short8*)(Kp + headoff + (size_t)srow * DM + sch * 8);
    short8 vpf = *(const short8*)(VT + vthead + (size_t)srow * SEQ + sch * 8);

    for (int kb = 0; kb < KBend; ++kb) {
      // ---- staged regs -> swizzled LDS (conflict-free) ----
      *(short8*)(&Ks[(sch * 64 + (srow ^ sch)) * 8]) = kpf;
      *(short8*)(&Vt[(sch * 64 + (srow ^ sch)) * 8]) = vpf;
      __syncthreads();
      // ---- issue next tile's global loads (hide under compute) ----
      if (kb + 1 < KBend) {
        kpf = *(const short8*)(Kp + headoff + (size_t)((kb + 1) * 64 + srow) * DM + sch * 8);
        vpf = *(const short8*)(VT + vthead + (size_t)srow * SEQ + (kb + 1) * 64 + sch * 8);
      }

      const bool active = (kb * 64) <= (qrow0 + 15);
      if (active) {
        // ---- QK^T swapped: D[s][q], s = kb*64 + sf*16 + rg*4 + r, q = qg ----
        short8 kf[4][2];
#pragma unroll
        for (int sf = 0; sf < 4; ++sf)
#pragma unroll
          for (int ck = 0; ck < 2; ++ck) {
            const int dc = ck * 4 + rg;
            kf[sf][ck] = *(const short8*)(&Ks[(dc * 64 + ((sf * 16 + fr) ^ dc)) * 8]);
          }
        f32x4 sc_[4];
#pragma unroll
        for (int sf = 0; sf < 4; ++sf) {
          f32x4 z = (f32x4){0.f, 0.f, 0.f, 0.f};
#pragma unroll
          for (int ck = 0; ck < 2; ++ck)
            z = __builtin_amdgcn_mfma_f32_16x16x32_bf16(kf[sf][ck], qf[ck], z, 0, 0, 0);
          sc_[sf] = z;
        }
        // ---- mask + in-register softmax (all 16 values are row qg) ----
        float rowmax = -3e38f;
#pragma unroll
        for (int sf = 0; sf < 4; ++sf)
#pragma unroll
          for (int r = 0; r < 4; ++r) {
            const int sg = kb * 64 + sf * 16 + rg * 4 + r;
            float v = sc_[sf][r];
            v = (sg <= qg) ? v : -3e38f;
            sc_[sf][r] = v;
            rowmax = fmaxf(rowmax, v);
          }
        rowmax = fmaxf(rowmax, __shfl_xor(rowmax, 16, 64));
        rowmax = fmaxf(rowmax, __shfl_xor(rowmax, 32, 64));
        const float mnew = fmaxf(m_run, rowmax);
        const float scl = __expf(m_run - mnew);
        m_run = mnew;
        float psum = 0.f;
#pragma unroll
        for (int sf = 0; sf < 4; ++sf)
#pragma unroll
          for (int r = 0; r < 4; ++r) {
            const float p = __expf(sc_[sf][r] - mnew);
            sc_[sf][r] = p;
            psum += p;
          }
        psum += __shfl_xor(psum, 16, 64);
        psum += __shfl_xor(psum, 32, 64);
        l_run = l_run * scl + psum;
        // ---- rescale accO (its rows are q = qrow0 + rg*4 + r) ----
        const float s0 = __shfl(scl, rg * 4 + 0, 64);
        const float s1 = __shfl(scl, rg * 4 + 1, 64);
        const float s2 = __shfl(scl, rg * 4 + 2, 64);
        const float s3 = __shfl(scl, rg * 4 + 3, 64);
#pragma unroll
        for (int df = 0; df < 4; ++df) {
          accO[df][0] *= s0; accO[df][1] *= s1;
          accO[df][2] *= s2; accO[df][3] *= s3;
        }
        // ---- pack P to bf16 pairs, redistribute via per-wave LDS strip ----
#pragma unroll
        for (int sf = 0; sf < 4; ++sf) {
          u32x2 pv;
          pv[0] = (unsigned)f2bf(sc_[sf][0]) | ((unsigned)f2bf(sc_[sf][1]) << 16);
          pv[1] = (unsigned)f2bf(sc_[sf][2]) | ((unsigned)f2bf(sc_[sf][3]) << 16);
          *(u32x2*)(&Pw[fr * 72 + (sf * 8 + rg * 2) * 2]) = pv;
        }
        short8 pa[2];
#pragma unroll
        for (int ck = 0; ck < 2; ++ck)
          pa[ck] = *(const short8*)(&Pw[fr * 72 + (ck * 16 + rg * 4) * 2]);
        // ---- PV: A = P[q][s], B = V[s][d] from swizzled Vt ----
#pragma unroll
        for (int df = 0; df < 4; ++df)
#pragma unroll
          for (int ck = 0; ck < 2; ++ck) {
            const int sc = ck * 4 + rg;
            const short8 vf = *(const short8*)(&Vt[(sc * 64 + ((df * 16 + fr) ^ sc)) * 8]);
            accO[df] = __builtin_amdgcn_mfma_f32_16x16x32_bf16(pa[ck], vf, accO[df], 0, 0, 0);
          }
      }
      __syncthreads();   // compute reads done before next staging overwrites
    }

    // ---- write O (bf16); accO row q = qrow0 + rg*4 + r ----
    const float l0 = __shfl(l_run, rg * 4 + 0, 64);
    const float l1 = __shfl(l_run, rg * 4 + 1, 64);
    const float l2 = __shfl(l_run, rg * 4 + 2, 64);
    const float l3 = __shfl(l_run, rg * 4 + 3, 64);
#pragma unroll
    for (int df = 0; df < 4; ++df) {
      const int d = df * 16 + fr;
      Op[headoff + (size_t)(qrow0 + rg * 4 + 0) * DM + d] = f2bf(accO[df][0] / l0);
      Op[headoff + (size_t)(qrow0 + rg * 4 + 1) * DM + d] = f2bf(accO[df][1] / l1);
      Op[headoff + (size_t)(qrow0 + rg * 4 + 2) * DM + d] = f2bf(accO[df][2] / l2);
      Op[headoff + (size_t)(qrow0 + rg * 4 + 3) * DM + d] = f2bf(accO[df][3] / l3);
    }
  }
}

extern "C" void kernel_launch(void* const* d_in, const int* in_sizes, int n_in,
                              void* d_out, int out_size, void* d_ws, size_t ws_size,
                              hipStream_t stream) {
  (void)in_sizes; (void)n_in; (void)out_size; (void)ws_size;
  const float* queries = (const float*)d_in[0];
  const float* keys    = (const float*)d_in[1];
  const float* values  = (const float*)d_in[2];
  const float* Wq = (const float*)d_in[3];
  const float* bq = (const float*)d_in[4];
  const float* Wk = (const float*)d_in[5];
  const float* bk = (const float*)d_in[6];
  const float* Wv = (const float*)d_in[7];
  const float* bv = (const float*)d_in[8];
  const float* Wo = (const float*)d_in[9];
  const float* bo = (const float*)d_in[10];
  float* out = (float*)d_out;

  char* ws = (char*)d_ws;
  const size_t MB = 1u << 20;
  u16* Qb  = (u16*)(ws);
  u16* Kb  = (u16*)(ws + 8 * MB);
  u16* VTg = (u16*)(ws + 16 * MB);
  u16* Ob  = (u16*)(ws + 24 * MB);
  u16* Wqb = (u16*)(ws + 48 * MB);
  u16* Wkb = (u16*)(ws + 50 * MB);
  u16* Wvb = (u16*)(ws + 52 * MB);
  u16* Wob = (u16*)(ws + 54 * MB);
  float* cosT = (float*)(ws + 56 * MB);
  float* sinT = (float*)(ws + 56 * MB + 256 * 1024);

  conv_w<<<dim3(512, 1, 5), 256, 0, stream>>>(
      Wq, Wk, Wv, Wo, Wqb, Wkb, Wvb, Wob, cosT, sinT);
  gemm_qkv<<<dim3(MROWS / 256, DM / 256, 3), 512, 0, stream>>>(
      queries, keys, values, Wqb, Wkb, Wvb, bq, bk, bv, Qb, Kb, VTg, cosT, sinT);
  flash_attn<<<dim3(SEQ / 256, NH, NB2), 512, 0, stream>>>(Qb, Kb, VTg, Ob);
  gemm_o<<<dim3(MROWS / 128, DM / 128), 256, 0, stream>>>(Ob, Wob, bo, out);
}

// Round 14
// 138.628 us; speedup vs baseline: 1.0954x; 1.0954x over previous
//
#include <hip/hip_runtime.h>
#include <math.h>

#define DM 1024
#define NH 16
#define HD 64
#define SEQ 2048
#define NB2 2
#define MROWS 4096   // NB2*SEQ

typedef unsigned short u16;
typedef __attribute__((ext_vector_type(8))) short short8;
typedef __attribute__((ext_vector_type(4))) float f32x4;
typedef __attribute__((ext_vector_type(2))) unsigned int u32x2;

#define GLOAD16(g, l) __builtin_amdgcn_global_load_lds( \
    (const __attribute__((address_space(1))) void*)(g),  \
    (__attribute__((address_space(3))) void*)(l), 16, 0, 0)

static __device__ __forceinline__ u16 f2bf(float f) {
  union { float f; unsigned u; } v; v.f = f;
  unsigned r = v.u + 0x7fffu + ((v.u >> 16) & 1u);
  return (u16)(r >> 16);
}

static __device__ __forceinline__ short8 cvt8(float4 a, float4 b) {
  short8 s;
  s[0] = (short)f2bf(a.x); s[1] = (short)f2bf(a.y);
  s[2] = (short)f2bf(a.z); s[3] = (short)f2bf(a.w);
  s[4] = (short)f2bf(b.x); s[5] = (short)f2bf(b.y);
  s[6] = (short)f2bf(b.z); s[7] = (short)f2bf(b.w);
  return s;
}

// z=0..6: f32->bf16 conversion of {queries,keys,values,Wq,Wk,Wv,Wo}; z=7: rope table
__global__ void conv_all(
    const float* __restrict__ q, const float* __restrict__ k, const float* __restrict__ v,
    const float* __restrict__ wq, const float* __restrict__ wk,
    const float* __restrict__ wv, const float* __restrict__ wo,
    u16* __restrict__ xq, u16* __restrict__ xk, u16* __restrict__ xv,
    u16* __restrict__ wqb, u16* __restrict__ wkb, u16* __restrict__ wvb, u16* __restrict__ wob,
    float* __restrict__ cosT, float* __restrict__ sinT)
{
  const int z = blockIdx.z;
  const int idx = blockIdx.x * blockDim.x + threadIdx.x;
  if (z == 7) {
    if (idx >= SEQ * 32) return;
    int l = idx >> 5, i = idx & 31;
    float invf = expf(-(float)i * (9.210340371976184f / 32.0f)); // 10000^(-i/32)
    float ang = (float)l * invf;
    float s, c;
    sincosf(ang, &s, &c);
    cosT[idx] = c; sinT[idx] = s;
    return;
  }
  const float* src; u16* dst; int n;
  switch (z) {
    case 0: src = q;  dst = xq;  n = MROWS * DM; break;
    case 1: src = k;  dst = xk;  n = MROWS * DM; break;
    case 2: src = v;  dst = xv;  n = MROWS * DM; break;
    case 3: src = wq; dst = wqb; n = DM * DM; break;
    case 4: src = wk; dst = wkb; n = DM * DM; break;
    case 5: src = wv; dst = wvb; n = DM * DM; break;
    default: src = wo; dst = wob; n = DM * DM; break;
  }
  const int base = idx * 8;
  if (base >= n) return;
  float4 a = *(const float4*)(src + base);
  float4 b = *(const float4*)(src + base + 4);
  *(short8*)(dst + base) = cvt8(a, b);
}

// ---------------- 256x256 fused QKV GEMM, phase-split pipeline (R12) ----------------
__global__ __launch_bounds__(512) void gemm_qkv(
    const u16* __restrict__ Xq, const u16* __restrict__ Xk, const u16* __restrict__ Xv,
    const u16* __restrict__ Wqb, const u16* __restrict__ Wkb, const u16* __restrict__ Wvb,
    const float* __restrict__ bq, const float* __restrict__ bk, const float* __restrict__ bv,
    u16* __restrict__ Qb, u16* __restrict__ Kb, u16* __restrict__ VT,
    const float* __restrict__ cosT, const float* __restrict__ sinT)
{
  __shared__ __align__(16) u16 SH[49152];   // 96 KB: 3 x 32KB buffers; reused as bounce
  const int z = blockIdx.z;
  const u16* A = (z == 0) ? Xq : (z == 1) ? Xk : Xv;
  const u16* W = (z == 0) ? Wqb : (z == 1) ? Wkb : Wvb;
  const float* bias = (z == 0) ? bq : (z == 1) ? bk : bv;
  const int row0 = blockIdx.x * 256, col0 = blockIdx.y * 256;

  const int tid = threadIdx.x;
  const int lane = tid & 63;
  const int wid = tid >> 6;       // 0..7
  const int wm = wid >> 2;        // M half (128 rows)
  const int wn = wid & 3;         // N quarter (64 cols)
  const int fr = lane & 15, kg = lane >> 4;

  const u16* ga = A + (size_t)(row0 + (tid & 255)) * DM + ((tid >> 8) << 3);
  const u16* gb = W + (size_t)(col0 + (tid & 255)) * DM + ((tid >> 8) << 3);
  const int lw = (wid >> 2) * 2048 + (wid & 3) * 512;   // wave-uniform; lane*16B implicit
  u16* B0 = SH;
  u16* B1 = SH + 16384;
  u16* B2 = SH + 32768;

  f32x4 acc[8][4];
#pragma unroll
  for (int m = 0; m < 8; ++m)
#pragma unroll
    for (int n = 0; n < 4; ++n) acc[m][n] = (f32x4){0.f, 0.f, 0.f, 0.f};

  auto issueA = [&](int t, u16* buf) {
    const int ko = t * 32;
    GLOAD16(ga + ko, buf + lw);
    GLOAD16(ga + ko + 16, buf + lw + 4096);
  };
  auto issueB = [&](int t, u16* buf) {
    const int ko = t * 32;
    GLOAD16(gb + ko, buf + 8192 + lw);
    GLOAD16(gb + ko + 16, buf + 8192 + lw + 4096);
  };

  auto phA = [&](const u16* bufR, u16* bufW, int t2, short8* bfr) {
    short8 afr[4];
#pragma unroll
    for (int m = 0; m < 4; ++m)
      afr[m] = *(const short8*)(&bufR[kg * 2048 + (wm * 128 + m * 16 + fr) * 8]);
#pragma unroll
    for (int n = 0; n < 4; ++n)
      bfr[n] = *(const short8*)(&bufR[8192 + kg * 2048 + (wn * 64 + n * 16 + fr) * 8]);
    if (t2 < 32) issueA(t2, bufW);
    __builtin_amdgcn_sched_barrier(0);
    __builtin_amdgcn_s_barrier();
    __builtin_amdgcn_sched_barrier(0);
    __builtin_amdgcn_s_setprio(1);
#pragma unroll
    for (int m = 0; m < 4; ++m)
#pragma unroll
      for (int n = 0; n < 4; ++n)
        acc[m][n] = __builtin_amdgcn_mfma_f32_16x16x32_bf16(afr[m], bfr[n], acc[m][n], 0, 0, 0);
    __builtin_amdgcn_s_setprio(0);
    __builtin_amdgcn_sched_barrier(0);
    __builtin_amdgcn_s_barrier();
    __builtin_amdgcn_sched_barrier(0);
  };
  auto phB = [&](const u16* bufR, u16* bufW, int t2, const short8* bfr) {
    short8 afr[4];
#pragma unroll
    for (int m = 0; m < 4; ++m)
      afr[m] = *(const short8*)(&bufR[kg * 2048 + (wm * 128 + (m + 4) * 16 + fr) * 8]);
    if (t2 < 32) issueB(t2, bufW);
    __builtin_amdgcn_sched_barrier(0);
    __builtin_amdgcn_s_barrier();
    __builtin_amdgcn_sched_barrier(0);
    __builtin_amdgcn_s_setprio(1);
#pragma unroll
    for (int m = 0; m < 4; ++m)
#pragma unroll
      for (int n = 0; n < 4; ++n)
        acc[m + 4][n] = __builtin_amdgcn_mfma_f32_16x16x32_bf16(afr[m], bfr[n], acc[m + 4][n], 0, 0, 0);
    __builtin_amdgcn_s_setprio(0);
  };

  issueA(0, B0); issueB(0, B0);
  issueA(1, B1); issueB(1, B1);

#define QSTEP(WLIT, bufR, bufW, t2) do {                            \
    asm volatile("s_waitcnt vmcnt(" WLIT ")" ::: "memory");         \
    __builtin_amdgcn_sched_barrier(0);                              \
    __builtin_amdgcn_s_barrier();                                   \
    __builtin_amdgcn_sched_barrier(0);                              \
    short8 bfr[4];                                                  \
    phA(bufR, bufW, t2, bfr);                                       \
    phB(bufR, bufW, t2, bfr);                                       \
  } while (0)

  for (int t = 0; t < 30; t += 3) {
    QSTEP("4", B0, B2, t + 2);
    QSTEP("4", B1, B0, t + 3);
    QSTEP("4", B2, B1, t + 4);
  }
  QSTEP("4", B0, B2, 32);   // no issue; waits tile 30 (31 in flight)
  QSTEP("0", B1, B2, 33);   // drain tile 31
#undef QSTEP

  if (z == 2) {
    // ---- transposed epilogue: VT[(nb*NH + e/64)*64 + e%64][sbase + s] = C[s][e] ----
    __syncthreads();   // last-step LDS reads done before SH reuse
    const int nb = row0 >> 11;
    const int sbase = row0 & (SEQ - 1);
#pragma unroll
    for (int p = 0; p < 4; ++p) {
      if (wn == p) {
#pragma unroll
        for (int n = 0; n < 4; ++n) {
          const int dcol = n * 16 + fr;
          const float bv = bias[col0 + p * 64 + dcol];
#pragma unroll
          for (int m = 0; m < 8; ++m)
#pragma unroll
            for (int r = 0; r < 4; ++r)
              SH[dcol * 264 + wm * 128 + m * 16 + kg * 4 + r] = f2bf(acc[m][n][r] + bv);
        }
      }
      __syncthreads();
      {
        const int dcol = tid >> 3, sq = tid & 7;   // 64 cols x 8 chunks of 32 u16
        const int e = col0 + p * 64 + dcol;
        u16* dst = VT + ((size_t)(nb * NH + (e >> 6)) * HD + (e & 63)) * SEQ + sbase + sq * 32;
#pragma unroll
        for (int j = 0; j < 4; ++j)
          *(short8*)(dst + j * 8) = *(const short8*)(&SH[dcol * 264 + sq * 32 + j * 8]);
      }
      __syncthreads();
    }
    return;
  }

  // ---- RoPE epilogue (z=0 Q, z=1 K) ----
  const float qscale = (z == 0) ? 0.125f : 1.0f;
  u16* Cb = (z == 0) ? Qb : Kb;
#pragma unroll
  for (int m = 0; m < 8; ++m) {
#pragma unroll
    for (int r = 0; r < 4; ++r) {
      const int rowg = row0 + wm * 128 + m * 16 + kg * 4 + r;
      const int l = rowg & (SEQ - 1);
#pragma unroll
      for (int n = 0; n < 4; ++n) {
        const int colg = col0 + wn * 64 + n * 16 + fr;
        const int i = n * 16 + fr;      // position within head (0..63)
        const int fi = i & 31;          // freq index
        const float c = cosT[l * 32 + fi];
        const float s = sinT[l * 32 + fi];
        const float v = acc[m][n][r] + bias[colg];
        const float pv = acc[m][n ^ 2][r] + bias[col0 + wn * 64 + ((n ^ 2) * 16 + fr)];
        const float o = v * c + ((i < 32) ? -pv : pv) * s;
        Cb[(size_t)rowg * DM + colg] = f2bf(o * qscale);
      }
    }
  }
}

// ---------------- 128x128 output-projection GEMM, phase-split pipeline (R12) ----------------
__global__ __launch_bounds__(256) void gemm_o(
    const u16* __restrict__ Ob, const u16* __restrict__ Wob,
    const float* __restrict__ bo, float* __restrict__ out)
{
  __shared__ __align__(16) u16 SH[24576];   // 48 KB
  const int row0 = blockIdx.x * 128, col0 = blockIdx.y * 128;
  const int tid = threadIdx.x;
  const int lane = tid & 63;
  const int w = tid >> 6;         // 0..3
  const int wr = w >> 1;          // M half (64 rows)
  const int wc = w & 1;           // N half (64 cols)
  const int fr = lane & 15, kg = lane >> 4;

  const u16* ga = Ob + (size_t)(row0 + (tid & 127)) * DM + ((tid >> 7) << 3);
  const u16* gb = Wob + (size_t)(col0 + (tid & 127)) * DM + ((tid >> 7) << 3);
  const int lw = w * 512;
  u16* B0 = SH;
  u16* B1 = SH + 8192;
  u16* B2 = SH + 16384;

  f32x4 acc[4][4];
#pragma unroll
  for (int m = 0; m < 4; ++m)
#pragma unroll
    for (int n = 0; n < 4; ++n) acc[m][n] = (f32x4){0.f, 0.f, 0.f, 0.f};

  auto issueA = [&](int t, u16* buf) {
    const int ko = t * 32;
    GLOAD16(ga + ko, buf + lw);
    GLOAD16(ga + ko + 16, buf + lw + 2048);
  };
  auto issueB = [&](int t, u16* buf) {
    const int ko = t * 32;
    GLOAD16(gb + ko, buf + 4096 + lw);
    GLOAD16(gb + ko + 16, buf + 4096 + lw + 2048);
  };

  auto phA = [&](const u16* bufR, u16* bufW, int t2, short8* bfr) {
    short8 afr[2];
#pragma unroll
    for (int m = 0; m < 2; ++m)
      afr[m] = *(const short8*)(&bufR[kg * 1024 + (wr * 64 + m * 16 + fr) * 8]);
#pragma unroll
    for (int n = 0; n < 4; ++n)
      bfr[n] = *(const short8*)(&bufR[4096 + kg * 1024 + (wc * 64 + n * 16 + fr) * 8]);
    if (t2 < 32) issueA(t2, bufW);
    __builtin_amdgcn_sched_barrier(0);
    __builtin_amdgcn_s_barrier();
    __builtin_amdgcn_sched_barrier(0);
    __builtin_amdgcn_s_setprio(1);
#pragma unroll
    for (int m = 0; m < 2; ++m)
#pragma unroll
      for (int n = 0; n < 4; ++n)
        acc[m][n] = __builtin_amdgcn_mfma_f32_16x16x32_bf16(afr[m], bfr[n], acc[m][n], 0, 0, 0);
    __builtin_amdgcn_s_setprio(0);
    __builtin_amdgcn_sched_barrier(0);
    __builtin_amdgcn_s_barrier();
    __builtin_amdgcn_sched_barrier(0);
  };
  auto phB = [&](const u16* bufR, u16* bufW, int t2, const short8* bfr) {
    short8 afr[2];
#pragma unroll
    for (int m = 0; m < 2; ++m)
      afr[m] = *(const short8*)(&bufR[kg * 1024 + (wr * 64 + (m + 2) * 16 + fr) * 8]);
    if (t2 < 32) issueB(t2, bufW);
    __builtin_amdgcn_sched_barrier(0);
    __builtin_amdgcn_s_barrier();
    __builtin_amdgcn_sched_barrier(0);
    __builtin_amdgcn_s_setprio(1);
#pragma unroll
    for (int m = 0; m < 2; ++m)
#pragma unroll
      for (int n = 0; n < 4; ++n)
        acc[m + 2][n] = __builtin_amdgcn_mfma_f32_16x16x32_bf16(afr[m], bfr[n], acc[m + 2][n], 0, 0, 0);
    __builtin_amdgcn_s_setprio(0);
  };

  issueA(0, B0); issueB(0, B0);
  issueA(1, B1); issueB(1, B1);

#define OSTEP(WLIT, bufR, bufW, t2) do {                            \
    asm volatile("s_waitcnt vmcnt(" WLIT ")" ::: "memory");         \
    __builtin_amdgcn_sched_barrier(0);                              \
    __builtin_amdgcn_s_barrier();                                   \
    __builtin_amdgcn_sched_barrier(0);                              \
    short8 bfr[4];                                                  \
    phA(bufR, bufW, t2, bfr);                                       \
    phB(bufR, bufW, t2, bfr);                                       \
  } while (0)

  for (int t = 0; t < 30; t += 3) {
    OSTEP("4", B0, B2, t + 2);
    OSTEP("4", B1, B0, t + 3);
    OSTEP("4", B2, B1, t + 4);
  }
  OSTEP("4", B0, B2, 32);
  OSTEP("0", B1, B2, 33);
#undef OSTEP

#pragma unroll
  for (int m = 0; m < 4; ++m) {
#pragma unroll
    for (int r = 0; r < 4; ++r) {
      const int rowg = row0 + wr * 64 + m * 16 + kg * 4 + r;
#pragma unroll
      for (int n = 0; n < 4; ++n) {
        const int colg = col0 + wc * 64 + n * 16 + fr;
        out[(size_t)rowg * DM + colg] = acc[m][n][r] + bo[colg];
      }
    }
  }
}

// Flash attention, causal. Grid-unrolled pairing: 512 blocks, one q-tile each;
// block b<256 -> (qe=b&15, h=b>>4, nb=0), b>=256 -> (qe=15-(p&15), h=p>>4, nb=1)
// so the two blocks round-robin-assigned to one CU have complementary work
// (qe + (15-qe) = const) -> balanced AND 2 blocks/CU = 4 waves/SIMD.
// Inner loop identical to the proven R12 version.
__global__ __launch_bounds__(512) void flash_attn(
    const u16* __restrict__ Qp, const u16* __restrict__ Kp,
    const u16* __restrict__ VT, u16* __restrict__ Op)
{
  __shared__ __align__(16) u16 Ks[4096];   // swizzled: chunk c = dc*64 + (s^dc), 16B chunks
  __shared__ __align__(16) u16 Vt[4096];   // swizzled: chunk c = sc*64 + (d^sc)
  __shared__ __align__(16) u16 Pl[9216];   // per-wave P strip: [fr][36 dwords], 144B row stride

  const int tid = threadIdx.x;
  const int lane = tid & 63;
  const int w = tid >> 6;                  // 0..7
  const int fr = lane & 15, rg = lane >> 4;

  const int bid = blockIdx.x;              // 0..511
  const int half = bid >> 8;               // nb
  const int p = bid & 255;
  const int qe = half ? (15 - (p & 15)) : (p & 15);
  const int h = p >> 4;
  const int nb = half;

  const size_t headoff = (size_t)nb * SEQ * DM + (size_t)h * HD;      // Q, K, O
  const size_t vthead = (size_t)(nb * NH + h) * HD * SEQ;             // V^T
  const int srow = tid >> 3;   // 0..63 (staging row: s for K, d for V^T)
  const int sch  = tid & 7;    // 16B chunk within row
  u16* Pw = &Pl[w * 1152];

  const int KBend = 2 * qe + 2;
  const int qrow0 = qe * 128 + w * 16;
  const int qg = qrow0 + fr;             // this lane's softmax q-row

  short8 qf[2];
#pragma unroll
  for (int ck = 0; ck < 2; ++ck)
    qf[ck] = *(const short8*)(Qp + headoff + (size_t)(qrow0 + fr) * DM + ck * 32 + rg * 8);

  f32x4 accO[4];
#pragma unroll
  for (int df = 0; df < 4; ++df) accO[df] = (f32x4){0.f, 0.f, 0.f, 0.f};
  float m_run = -3e38f, l_run = 0.f;

  // prefetch kb=0 (one 16B chunk of K and V^T per thread)
  short8 kpf = *(const short8*)(Kp + headoff + (size_t)srow * DM + sch * 8);
  short8 vpf = *(const short8*)(VT + vthead + (size_t)srow * SEQ + sch * 8);

  for (int kb = 0; kb < KBend; ++kb) {
    // ---- staged regs -> swizzled LDS (conflict-free) ----
    *(short8*)(&Ks[(sch * 64 + (srow ^ sch)) * 8]) = kpf;
    *(short8*)(&Vt[(sch * 64 + (srow ^ sch)) * 8]) = vpf;
    __syncthreads();
    // ---- issue next tile's global loads (hide under compute) ----
    if (kb + 1 < KBend) {
      kpf = *(const short8*)(Kp + headoff + (size_t)((kb + 1) * 64 + srow) * DM + sch * 8);
      vpf = *(const short8*)(VT + vthead + (size_t)srow * SEQ + (kb + 1) * 64 + sch * 8);
    }

    const bool active = (kb * 64) <= (qrow0 + 15);
    if (active) {
      // ---- QK^T swapped: D[s][q], s = kb*64 + sf*16 + rg*4 + r, q = qg ----
      short8 kf[4][2];
#pragma unroll
      for (int sf = 0; sf < 4; ++sf)
#pragma unroll
        for (int ck = 0; ck < 2; ++ck) {
          const int dc = ck * 4 + rg;
          kf[sf][ck] = *(const short8*)(&Ks[(dc * 64 + ((sf * 16 + fr) ^ dc)) * 8]);
        }
      f32x4 sc_[4];
#pragma unroll
      for (int sf = 0; sf < 4; ++sf) {
        f32x4 z = (f32x4){0.f, 0.f, 0.f, 0.f};
#pragma unroll
        for (int ck = 0; ck < 2; ++ck)
          z = __builtin_amdgcn_mfma_f32_16x16x32_bf16(kf[sf][ck], qf[ck], z, 0, 0, 0);
        sc_[sf] = z;
      }
      // ---- mask + in-register softmax (all 16 values are row qg) ----
      float rowmax = -3e38f;
#pragma unroll
      for (int sf = 0; sf < 4; ++sf)
#pragma unroll
        for (int r = 0; r < 4; ++r) {
          const int sg = kb * 64 + sf * 16 + rg * 4 + r;
          float v = sc_[sf][r];
          v = (sg <= qg) ? v : -3e38f;
          sc_[sf][r] = v;
          rowmax = fmaxf(rowmax, v);
        }
      rowmax = fmaxf(rowmax, __shfl_xor(rowmax, 16, 64));
      rowmax = fmaxf(rowmax, __shfl_xor(rowmax, 32, 64));
      const float mnew = fmaxf(m_run, rowmax);
      const float scl = __expf(m_run - mnew);
      m_run = mnew;
      float psum = 0.f;
#pragma unroll
      for (int sf = 0; sf < 4; ++sf)
#pragma unroll
        for (int r = 0; r < 4; ++r) {
          const float pp = __expf(sc_[sf][r] - mnew);
          sc_[sf][r] = pp;
          psum += pp;
        }
      psum += __shfl_xor(psum, 16, 64);
      psum += __shfl_xor(psum, 32, 64);
      l_run = l_run * scl + psum;
      // ---- rescale accO (its rows are q = qrow0 + rg*4 + r) ----
      const float s0 = __shfl(scl, rg * 4 + 0, 64);
      const float s1 = __shfl(scl, rg * 4 + 1, 64);
      const float s2 = __shfl(scl, rg * 4 + 2, 64);
      const float s3 = __shfl(scl, rg * 4 + 3, 64);
#pragma unroll
      for (int df = 0; df < 4; ++df) {
        accO[df][0] *= s0; accO[df][1] *= s1;
        accO[df][2] *= s2; accO[df][3] *= s3;
      }
      // ---- pack P to bf16 pairs, redistribute via per-wave LDS strip ----
#pragma unroll
      for (int sf = 0; sf < 4; ++sf) {
        u32x2 pv;
        pv[0] = (unsigned)f2bf(sc_[sf][0]) | ((unsigned)f2bf(sc_[sf][1]) << 16);
        pv[1] = (unsigned)f2bf(sc_[sf][2]) | ((unsigned)f2bf(sc_[sf][3]) << 16);
        *(u32x2*)(&Pw[fr * 72 + (sf * 8 + rg * 2) * 2]) = pv;
      }
      short8 pa[2];
#pragma unroll
      for (int ck = 0; ck < 2; ++ck)
        pa[ck] = *(const short8*)(&Pw[fr * 72 + (ck * 16 + rg * 4) * 2]);
      // ---- PV: A = P[q][s], B = V[s][d] from swizzled Vt ----
#pragma unroll
      for (int df = 0; df < 4; ++df)
#pragma unroll
        for (int ck = 0; ck < 2; ++ck) {
          const int sc = ck * 4 + rg;
          const short8 vf = *(const short8*)(&Vt[(sc * 64 + ((df * 16 + fr) ^ sc)) * 8]);
          accO[df] = __builtin_amdgcn_mfma_f32_16x16x32_bf16(pa[ck], vf, accO[df], 0, 0, 0);
        }
    }
    __syncthreads();   // compute reads done before next staging overwrites
  }

  // ---- write O (bf16); accO row q = qrow0 + rg*4 + r ----
  const float l0 = __shfl(l_run, rg * 4 + 0, 64);
  const float l1 = __shfl(l_run, rg * 4 + 1, 64);
  const float l2 = __shfl(l_run, rg * 4 + 2, 64);
  const float l3 = __shfl(l_run, rg * 4 + 3, 64);
#pragma unroll
  for (int df = 0; df < 4; ++df) {
    const int d = df * 16 + fr;
    Op[headoff + (size_t)(qrow0 + rg * 4 + 0) * DM + d] = f2bf(accO[df][0] / l0);
    Op[headoff + (size_t)(qrow0 + rg * 4 + 1) * DM + d] = f2bf(accO[df][1] / l1);
    Op[headoff + (size_t)(qrow0 + rg * 4 + 2) * DM + d] = f2bf(accO[df][2] / l2);
    Op[headoff + (size_t)(qrow0 + rg * 4 + 3) * DM + d] = f2bf(accO[df][3] / l3);
  }
}

extern "C" void kernel_launch(void* const* d_in, const int* in_sizes, int n_in,
                              void* d_out, int out_size, void* d_ws, size_t ws_size,
                              hipStream_t stream) {
  (void)in_sizes; (void)n_in; (void)out_size; (void)ws_size;
  const float* queries = (const float*)d_in[0];
  const float* keys    = (const float*)d_in[1];
  const float* values  = (const float*)d_in[2];
  const float* Wq = (const float*)d_in[3];
  const float* bq = (const float*)d_in[4];
  const float* Wk = (const float*)d_in[5];
  const float* bk = (const float*)d_in[6];
  const float* Wv = (const float*)d_in[7];
  const float* bv = (const float*)d_in[8];
  const float* Wo = (const float*)d_in[9];
  const float* bo = (const float*)d_in[10];
  float* out = (float*)d_out;

  char* ws = (char*)d_ws;
  const size_t MB = 1u << 20;
  u16* Qb  = (u16*)(ws);
  u16* Kb  = (u16*)(ws + 8 * MB);
  u16* VTg = (u16*)(ws + 16 * MB);
  u16* Xq  = (u16*)(ws + 24 * MB);   // Ob aliases Xq (Xq dead after gemm_qkv)
  u16* Ob  = Xq;
  u16* Xk  = (u16*)(ws + 32 * MB);
  u16* Xv  = (u16*)(ws + 40 * MB);
  u16* Wqb = (u16*)(ws + 48 * MB);
  u16* Wkb = (u16*)(ws + 50 * MB);
  u16* Wvb = (u16*)(ws + 52 * MB);
  u16* Wob = (u16*)(ws + 54 * MB);
  float* cosT = (float*)(ws + 56 * MB);
  float* sinT = (float*)(ws + 56 * MB + 256 * 1024);

  conv_all<<<dim3(2048, 1, 8), 256, 0, stream>>>(
      queries, keys, values, Wq, Wk, Wv, Wo,
      Xq, Xk, Xv, Wqb, Wkb, Wvb, Wob, cosT, sinT);
  gemm_qkv<<<dim3(MROWS / 256, DM / 256, 3), 512, 0, stream>>>(
      Xq, Xk, Xv, Wqb, Wkb, Wvb, bq, bk, bv, Qb, Kb, VTg, cosT, sinT);
  flash_attn<<<dim3(512, 1, 1), 512, 0, stream>>>(Qb, Kb, VTg, Ob);
  gemm_o<<<dim3(MROWS / 128, DM / 128), 256, 0, stream>>>(Ob, Wob, bo, out);
}